// Round 15
// baseline (469.573 us; speedup 1.0000x reference)
//
#include <hip/hip_runtime.h>
#include <stdint.h>

// ---------------------------------------------------------------------------
// decoder_80487687127254 : B=4096 T=7 H=512 L=256 D=1024
// ---------------------------------------------------------------------------

typedef __attribute__((ext_vector_type(4))) float f32x4;
typedef __attribute__((ext_vector_type(8))) short bf16x8;
typedef __attribute__((ext_vector_type(4))) unsigned short us4;

__device__ __forceinline__ unsigned short f2b(float f) {
  union { float f; unsigned u; } x; x.f = f;
  unsigned r = x.u + 0x7FFFu + ((x.u >> 16) & 1u);   // RNE
  return (unsigned short)(r >> 16);
}
__device__ __forceinline__ float b2f(unsigned short s) {
  union { unsigned u; float f; } x; x.u = ((unsigned)s) << 16; return x.f;
}
__device__ __forceinline__ float sigmoidf(float x) {
  return 1.f / (1.f + __expf(-x));
}
__device__ __forceinline__ float fast_tanh(float x) {
  x = fminf(15.f, fmaxf(-15.f, x));
  float e = __expf(2.f * x);
  return (e - 1.f) / (e + 1.f);
}

// async global->LDS, 16B per lane; LDS dest must be wave-uniform (HW adds lane*16)
__device__ __forceinline__ void gl_lds16(const void* g, void* l) {
  auto gp = reinterpret_cast<const __attribute__((address_space(1))) unsigned int*>(
      reinterpret_cast<uintptr_t>(g));
  auto lp = reinterpret_cast<__attribute__((address_space(3))) unsigned int*>(
      reinterpret_cast<uintptr_t>(l));
  __builtin_amdgcn_global_load_lds(gp, lp, 16, 0, 0);
}

template <int N>
__device__ __forceinline__ void gate() {
  if constexpr (N == 8) asm volatile("s_waitcnt vmcnt(8)" ::: "memory");
  else if constexpr (N == 4) asm volatile("s_waitcnt vmcnt(4)" ::: "memory");
  else asm volatile("s_waitcnt vmcnt(0)" ::: "memory");
}

// ===========================================================================
// 2-phase GEMM cores (wave tile 128x64, BK=32, dbuf): the verified plateau
// structure (~670 TF, MfmaUtil 27%) used for lstm/rep.
// gemm_emb gets the R15 8-phase-style ring-4 core (see below).
// ===========================================================================

// stage a 256x32 tile (16 KB): 4 gl_lds per thread (256 threads).
__device__ __forceinline__ void stage256x32(const unsigned short* src, int ld,
                                            unsigned short* hbase, int tid) {
  const int row_in = tid >> 2;   // 0..63
  const int gidx = tid & 3;
#pragma unroll
  for (int r = 0; r < 4; ++r) {
    int row = r * 64 + row_in;
    int gsrc = gidx ^ ((row >> 1) & 3);
    gl_lds16(src + (size_t)row * ld + gsrc * 8, hbase + r * 2048 + (tid >> 6) * 512);
  }
}

// stage a 128x32 tile (8 KB): 2 gl_lds per thread (256 threads).
__device__ __forceinline__ void stage128x32(const unsigned short* src, int ld,
                                            unsigned short* hbase, int tid) {
  const int row_in = tid >> 2;   // 0..63
  const int gidx = tid & 3;
#pragma unroll
  for (int r = 0; r < 2; ++r) {
    int row = r * 64 + row_in;
    int gsrc = gidx ^ ((row >> 1) & 3);
    gl_lds16(src + (size_t)row * ld + gsrc * 8, hbase + r * 2048 + (tid >> 6) * 512);
  }
}

// stage a 256x32 tile with 512 threads: 2 gl_lds per thread.
__device__ __forceinline__ void stage256x32_t512(const unsigned short* src, int ld,
                                                 unsigned short* hbase, int tid) {
  const int row_in = tid >> 2;   // 0..127
  const int gidx = tid & 3;
#pragma unroll
  for (int r = 0; r < 2; ++r) {
    int row = r * 128 + row_in;
    int gsrc = gidx ^ ((row >> 1) & 3);
    gl_lds16(src + (size_t)row * ld + gsrc * 8, hbase + r * 4096 + (tid >> 6) * 512);
  }
}

__device__ __forceinline__ bf16x8 lds_fragH(const unsigned short* hbase, int row, int lq) {
  return *(const bf16x8*)(hbase + row * 32 + (lq ^ (((row >> 1) & 3) << 3)));
}

// one K-tile (BK=32), wave tile 128x64: 12 ds_read_b128 + 32 MFMA (2-phase core)
__device__ __forceinline__ void tile_w128(const unsigned short* Ab, const unsigned short* Bb,
                                          int wm, int wn, int lane, f32x4 (&acc)[8][4]) {
  const int lr = lane & 15, lq = (lane >> 4) * 8;
  bf16x8 b[4];
#pragma unroll
  for (int n = 0; n < 4; ++n) b[n] = lds_fragH(Bb, wn * 64 + n * 16 + lr, lq);
  bf16x8 a[8];
#pragma unroll
  for (int i = 0; i < 8; ++i) a[i] = lds_fragH(Ab, wm * 128 + i * 16 + lr, lq);
  __builtin_amdgcn_s_setprio(1);
#pragma unroll
  for (int i = 0; i < 8; ++i)
#pragma unroll
    for (int n = 0; n < 4; ++n)
      acc[i][n] = __builtin_amdgcn_mfma_f32_16x16x32_bf16(a[i], b[n], acc[i][n], 0, 0, 0);
  __builtin_amdgcn_s_setprio(0);
}

#define DBUF_SYNC()                                   \
  asm volatile("s_waitcnt vmcnt(0)" ::: "memory");    \
  __builtin_amdgcn_s_barrier();                       \
  __builtin_amdgcn_sched_barrier(0);

// ---------------------------------------------------------------------------
// legacy 128x128 2-phase BK=64 core (kept for gemm_rep)
// ---------------------------------------------------------------------------
__device__ __forceinline__ void stage128x64(const unsigned short* src, int ld,
                                            unsigned short* lds, int wv, int lane) {
#pragma unroll
  for (int r = 0; r < 4; ++r) {
    int row = r * 32 + wv * 8 + (lane >> 3);
    gl_lds16(src + (size_t)row * ld + (lane & 7) * 8, lds + (r * 32 + wv * 8) * 64);
  }
}
__device__ __forceinline__ void mfma_tile(const unsigned short* As, const unsigned short* Bs,
                                          int wm, int wn, int lane, f32x4 acc[4][4]) {
#pragma unroll
  for (int kk = 0; kk < 2; ++kk) {
    int ko = kk * 32 + (lane >> 4) * 8;
    bf16x8 a[4], b[4];
#pragma unroll
    for (int i = 0; i < 4; ++i)
      a[i] = *(const bf16x8*)(As + (size_t)(wm * 64 + i * 16 + (lane & 15)) * 64 + ko);
#pragma unroll
    for (int i = 0; i < 4; ++i)
      b[i] = *(const bf16x8*)(Bs + (size_t)(wn * 64 + i * 16 + (lane & 15)) * 64 + ko);
#pragma unroll
    for (int mi = 0; mi < 4; ++mi)
#pragma unroll
      for (int ni = 0; ni < 4; ++ni)
        acc[mi][ni] = __builtin_amdgcn_mfma_f32_16x16x32_bf16(a[mi], b[ni], acc[mi][ni], 0, 0, 0);
  }
}

// ---------------------------------------------------------------------------
// pack, x4-vectorized (verified R13/R14)
// ---------------------------------------------------------------------------
__global__ __launch_bounds__(256) void pack_kernel(
    const float* __restrict__ noise, const float* __restrict__ erep_w,
    const float* __restrict__ emb_w,
    const float* __restrict__ wih_f, const float* __restrict__ whh_f,
    const float* __restrict__ bih_f, const float* __restrict__ bhh_f,
    const float* __restrict__ wih_b, const float* __restrict__ whh_b,
    const float* __restrict__ bih_b, const float* __restrict__ bhh_b,
    unsigned short* __restrict__ noiseb, unsigned short* __restrict__ erepT,
    unsigned short* __restrict__ embT, unsigned short* __restrict__ lstmW,
    float* __restrict__ lstmB) {
  const int N0 = 4096 * 256 / 4;
  const int N1 = 1792 * 256 / 4;
  const int N2 = 1024 * 1024 / 4;
  const int N3 = 2 * 2048 * 768 / 4;
  const int N4 = 2 * 2048 / 4;
  const int total = N0 + N1 + N2 + N3 + N4;
  for (int i = blockIdx.x * 256 + threadIdx.x; i < total; i += gridDim.x * 256) {
    int x = i;
    if (x < N0) {
      f32x4 v = ((const f32x4*)noise)[x];
      us4 o4;
#pragma unroll
      for (int e = 0; e < 4; ++e) o4[e] = f2b(v[e]);
      ((us4*)noiseb)[x] = o4;
      continue;
    }
    x -= N0;
    if (x < N1) {
      int n = x >> 6, k4 = (x & 63) * 4;
      us4 o4;
#pragma unroll
      for (int e = 0; e < 4; ++e) o4[e] = f2b(erep_w[(size_t)(k4 + e) * 1792 + n]);
      ((us4*)erepT)[x] = o4;
      continue;
    }
    x -= N1;
    if (x < N2) {
      int n = x >> 8, k4 = (x & 255) * 4;
      int o = (n & 63) * 16 + (n >> 6);
      us4 o4;
#pragma unroll
      for (int e = 0; e < 4; ++e) o4[e] = f2b(emb_w[(size_t)(k4 + e) * 1024 + o]);
      ((us4*)embT)[x] = o4;
      continue;
    }
    x -= N2;
    if (x < N3) {
      int dir = x / (2048 * 192);
      int r = x - dir * (2048 * 192);
      int npk = r / 192, k4 = (r - npk * 192) * 4;
      int blk = npk >> 6, g = (npk >> 4) & 3, u = npk & 15;
      int o = g * 512 + blk * 16 + u;
      const float* wih = dir ? wih_b : wih_f;
      const float* whh = dir ? whh_b : whh_f;
      us4 o4;
#pragma unroll
      for (int e = 0; e < 4; ++e) {
        int k = k4 + e;
        float v = (k < 256) ? wih[(size_t)k * 2048 + o] : whh[(size_t)(k - 256) * 2048 + o];
        o4[e] = f2b(v);
      }
      ((us4*)lstmW)[x] = o4;
      continue;
    }
    x -= N3;
    {
      int dir = x >> 9, npk4 = (x & 511) * 4;
      int blk = npk4 >> 6, g = (npk4 >> 4) & 3, u = npk4 & 15;
      int o = g * 512 + blk * 16 + u;
      const float* bi = dir ? bih_b : bih_f;
      const float* bh = dir ? bhh_b : bhh_f;
      f32x4 o4;
#pragma unroll
      for (int e = 0; e < 4; ++e) o4[e] = bi[o + e] + bh[o + e];
      ((f32x4*)lstmB)[x] = o4;
    }
  }
}

// ---------------------------------------------------------------------------
// rep = softsign(noise @ erep_w + b)
// ---------------------------------------------------------------------------
__global__ __launch_bounds__(256) void gemm_rep_kernel(
    const unsigned short* __restrict__ A, const unsigned short* __restrict__ Bt,
    const float* __restrict__ bias, unsigned short* __restrict__ rep_t) {
  __shared__ unsigned short As[128 * 64];
  __shared__ unsigned short Bs[128 * 64];
  const int lane = threadIdx.x & 63, wv = threadIdx.x >> 6;
  const int wm = wv >> 1, wn = wv & 1;
  const int m0 = blockIdx.y * 128, n0 = blockIdx.x * 128;
  f32x4 acc[4][4];
#pragma unroll
  for (int i = 0; i < 4; ++i)
#pragma unroll
    for (int j = 0; j < 4; ++j) acc[i][j] = (f32x4){0.f, 0.f, 0.f, 0.f};
  for (int k0 = 0; k0 < 256; k0 += 64) {
    stage128x64(A + (size_t)m0 * 256 + k0, 256, As, wv, lane);
    stage128x64(Bt + (size_t)n0 * 256 + k0, 256, Bs, wv, lane);
    __syncthreads();
    mfma_tile(As, Bs, wm, wn, lane, acc);
    __syncthreads();
  }
#pragma unroll
  for (int ni = 0; ni < 4; ++ni) {
    int n = n0 + wn * 64 + ni * 16 + (lane & 15);
    float bv = bias[n];
    int t = n >> 8, l = n & 255;
#pragma unroll
    for (int mi = 0; mi < 4; ++mi)
#pragma unroll
      for (int r = 0; r < 4; ++r) {
        int m = m0 + wm * 64 + mi * 16 + (lane >> 4) * 4 + r;
        float v = acc[mi][ni][r] + bv;
        v = v / (1.f + fabsf(v));
        rep_t[((size_t)t * 4096 + m) * 256 + l] = f2b(v);
      }
  }
}

// ---------------------------------------------------------------------------
// LSTM step (unchanged R14): 256x128 block / 128x64 wave 2-phase core.
// ---------------------------------------------------------------------------
template <int NT>
__global__ __launch_bounds__(256, 2) void lstm_step_kernel(
    const unsigned short* __restrict__ rep_t, const unsigned short* __restrict__ Wp,
    const float* __restrict__ biasP, unsigned short* __restrict__ cbuf,
    unsigned short* __restrict__ lstm1, int step) {
  __shared__ unsigned short Ar[2][8192];
  __shared__ unsigned short Br[2][4096];
  const int tid = threadIdx.x, lane = tid & 63, wv = tid >> 6;
  const int wm = wv >> 1, wn = wv & 1;
  const int swz = (blockIdx.x & 7) * 64 + (blockIdx.x >> 3);
  const int dir = swz >> 8;
  const int rem = swz & 255;
  const int by = rem >> 4, bx = rem & 15;
  const int m0 = by * 256, n0 = bx * 128;
  const int t_proc = dir ? (6 - step) : step;
  const int t_prev = dir ? (t_proc + 1) : (t_proc - 1);
  const unsigned short* W = Wp + (size_t)dir * 2048 * 768;
  unsigned short* cp = cbuf + (size_t)dir * (4096 * 512);
  const unsigned short* xsrc = rep_t + (size_t)t_proc * 4096 * 256;
  const unsigned short* hsrc =
      lstm1 + (size_t)((NT == 24) ? t_prev : 0) * 1024 + (size_t)dir * 512;

  f32x4 acc[8][4];
#pragma unroll
  for (int i = 0; i < 8; ++i)
#pragma unroll
    for (int j = 0; j < 4; ++j) acc[i][j] = (f32x4){0.f, 0.f, 0.f, 0.f};

  auto asrc = [&](int tt) {
    return tt < 8 ? xsrc + (size_t)m0 * 256 + tt * 32
                  : hsrc + (size_t)m0 * 7168 + (tt - 8) * 32;
  };
  auto ald = [&](int tt) { return tt < 8 ? 256 : 7168; };

  stage256x32(asrc(0), ald(0), Ar[0], tid);
  stage128x32(W + (size_t)n0 * 768 + 0 * 32, 768, Br[0], tid);
  DBUF_SYNC()

#pragma unroll
  for (int t = 0; t < NT; ++t) {
    if (t + 1 < NT) {
      stage256x32(asrc(t + 1), ald(t + 1), Ar[(t + 1) & 1], tid);
      stage128x32(W + (size_t)n0 * 768 + (t + 1) * 32, 768, Br[(t + 1) & 1], tid);
    }
    tile_w128(Ar[t & 1], Br[t & 1], wm, wn, lane, acc);
    if (t + 1 < NT) { DBUF_SYNC() }
  }

  const int u = lane & 15;
  const int blk = (n0 + wn * 64) >> 6;
  const int j = blk * 16 + u;
  const float bz0 = biasP[dir * 2048 + blk * 64 + 0 * 16 + u];
  const float bz1 = biasP[dir * 2048 + blk * 64 + 1 * 16 + u];
  const float bz2 = biasP[dir * 2048 + blk * 64 + 2 * 16 + u];
  const float bz3 = biasP[dir * 2048 + blk * 64 + 3 * 16 + u];
#pragma unroll
  for (int mi = 0; mi < 8; ++mi)
#pragma unroll
    for (int r = 0; r < 4; ++r) {
      int row = m0 + wm * 128 + mi * 16 + (lane >> 4) * 4 + r;
      float gi = acc[mi][0][r] + bz0;
      float gf = acc[mi][1][r] + bz1;
      float gg = acc[mi][2][r] + bz2;
      float go = acc[mi][3][r] + bz3;
      size_t ci = (size_t)row * 512 + j;
      float c;
      if (NT == 8) {
        c = sigmoidf(gi) * fast_tanh(gg);
      } else {
        c = sigmoidf(gf) * b2f(cp[ci]) + sigmoidf(gi) * fast_tanh(gg);
      }
      cp[ci] = f2b(c);
      float h = sigmoidf(go) * fast_tanh(c);
      lstm1[((size_t)row * 7 + t_proc) * 1024 + dir * 512 + j] = f2b(h);
    }
}

// ---------------------------------------------------------------------------
// Fused attention v3 (unchanged)
// ---------------------------------------------------------------------------
__global__ __launch_bounds__(256) void att_fused3_kernel(
    const float* __restrict__ enc, const unsigned short* __restrict__ lstm1,
    unsigned short* __restrict__ att) {
  __shared__ unsigned short Qs[7 * 1032];
  __shared__ unsigned short Es[7 * 1032];
  __shared__ float P[8 * 256];
  __shared__ float sG[98];
  __shared__ float sC[7][14];
  __shared__ float sA[16];
  const int tid = threadIdx.x, lane = tid & 63, wv = tid >> 6;
  const int b = blockIdx.x;
  const float* Eb = enc + (size_t)b * 7168;
  const unsigned short* Qb = lstm1 + (size_t)b * 7168;

  if (tid < 98) ((float*)sC)[tid] = 0.f;

  const f32x4* Eb4 = (const f32x4*)Eb;
  const int d0 = tid * 4;
#pragma unroll
  for (int r = 0; r < 7; ++r) {
    f32x4 v = Eb4[r * 256 + tid];
    us4 hi;
#pragma unroll
    for (int e = 0; e < 4; ++e) hi[e] = f2b(v[e]);
    *(us4*)&Es[r * 1032 + d0] = hi;
    *(us4*)&Qs[r * 1032 + d0] = *(const us4*)(Qb + r * 1024 + d0);
  }
  asm volatile("s_waitcnt lgkmcnt(0)" ::: "memory");
  __builtin_amdgcn_sched_barrier(0);

  {
    const int rr = lane & 15;
    const int rowc = rr % 7;
    const int kbase = wv * 256 + (lane >> 4) * 8;
    f32x4 g1 = {0.f, 0.f, 0.f, 0.f}, g2 = {0.f, 0.f, 0.f, 0.f};
#pragma unroll
    for (int s = 0; s < 8; ++s) {
      const int k0 = kbase + s * 32;
      bf16x8 aq = *(const bf16x8*)&Qs[rowc * 1032 + k0];
      bf16x8 be = *(const bf16x8*)&Es[rowc * 1032 + k0];
      g1 = __builtin_amdgcn_mfma_f32_16x16x32_bf16(aq, be, g1, 0, 0, 0);
      g2 = __builtin_amdgcn_mfma_f32_16x16x32_bf16(aq, aq, g2, 0, 0, 0);
    }
    *(f32x4*)&P[((wv * 2 + 0) * 64 + lane) * 4] = g1;
    *(f32x4*)&P[((wv * 2 + 1) * 64 + lane) * 4] = g2;
  }
  __syncthreads();

  if (tid < 98) {
    int i = tid / 14, v = tid - i * 14;
    int col = v < 7 ? v : v - 7;
    int tile = v < 7 ? 0 : 1;
    int ln = ((i >> 2) << 4) | col;
    int rg = i & 3;
    float s = 0.f;
#pragma unroll
    for (int w = 0; w < 4; ++w) s += P[((w * 2 + tile) * 64 + ln) * 4 + rg];
    sG[i * 14 + v] = s;
  }
  __syncthreads();
  if (wv == 0) {
    for (int i = 0; i < 7; ++i) {
      const int nt = 7 + i;
      float s = -1e30f;
      if (lane < 7) {
        s = sG[i * 14 + lane];
      } else if (lane < nt) {
        int jj = lane - 7;
        float a2 = 0.f;
#pragma unroll
        for (int v = 0; v < 14; ++v) a2 += sC[jj][v] * sG[i * 14 + v];
        s = a2;
      }
      float mx = s;
#pragma unroll
      for (int off = 8; off >= 1; off >>= 1) mx = fmaxf(mx, __shfl_xor(mx, off, 16));
      float e = (lane < nt) ? __expf(s - mx) : 0.f;
      float sum = e;
#pragma unroll
      for (int off = 8; off >= 1; off >>= 1) sum += __shfl_xor(sum, off, 16);
      float aw = e / sum;
      if (lane < 16) sA[lane] = aw;
      if (lane < 14) {
        float c = (lane < 7) ? sA[lane] : 0.f;
        for (int jj = 0; jj < i; ++jj) c += sA[7 + jj] * sC[jj][lane];
        if (lane == 7 + i) c += 1.f;
        sC[i][lane] = c;
      }
    }
  }
  __syncthreads();

  {
    float acc[7][4];
#pragma unroll
    for (int i = 0; i < 7; ++i)
#pragma unroll
      for (int e = 0; e < 4; ++e) acc[i][e] = 0.f;
#pragma unroll
    for (int t = 0; t < 7; ++t) {
      us4 ev = *(const us4*)&Es[t * 1032 + d0];
      float evf[4];
#pragma unroll
      for (int e = 0; e < 4; ++e) evf[e] = b2f(ev[e]);
#pragma unroll
      for (int i = 0; i < 7; ++i) {
        float c = sC[i][t];
#pragma unroll
        for (int e = 0; e < 4; ++e) acc[i][e] += c * evf[e];
      }
    }
#pragma unroll
    for (int m = 0; m < 7; ++m) {
      us4 qv = *(const us4*)&Qs[m * 1032 + d0];
      float qf[4];
#pragma unroll
      for (int e = 0; e < 4; ++e) qf[e] = b2f(qv[e]);
#pragma unroll
      for (int i = m; i < 7; ++i) {
        float c = sC[i][7 + m];
#pragma unroll
        for (int e = 0; e < 4; ++e) acc[i][e] += c * qf[e];
      }
    }
    unsigned short* Ab = att + (size_t)b * 7168;
#pragma unroll
    for (int i = 0; i < 7; ++i) {
      us4 r;
#pragma unroll
      for (int e = 0; e < 4; ++e) r[e] = f2b(acc[i][e]);
      *(us4*)(Ab + i * 1024 + d0) = r;
    }
  }
}

// ---------------------------------------------------------------------------
// gemm_emb, 8-phase-style ring-4 core (R15 final attempt).
// 512 thr / 8 waves (wm=wv>>2, wn=wv&3), BM=BN=256, BK=32, ring-4 LDS 128 KB.
// Per K-tile t, 2 phases:
//   ph0 pre-window: read b0-3 + a0-3 (tile t), stage A(t+3) -> slot (t+3)&3
//   barrier; lgkm(0); setprio; 16 MFMA (mi0-3); setprio
//   ph1 pre-window: read a4-7, stage B(t+3), gate vmcnt(8) [certifies t+1]
//   barrier; lgkm(0); setprio; 16 MFMA (mi4-7); setprio
// Race analysis: slot (t+3)&3 held tile t-1, all of whose reads precede
// t-1.ph1's barrier < t's group.  Gate at t.ph1: newest 8 loads =
// tiles t+2,t+3's stages; tile t+1's loads are older -> drained; the
// barrier then publishes them for t+1.ph0's pre-window reads.
// Tail gates: t=29 -> vmcnt(4), t=30 -> vmcnt(0).
// ---------------------------------------------------------------------------
__global__ __launch_bounds__(512, 1) void gemm_emb8p_kernel(
    const unsigned short* __restrict__ A, const unsigned short* __restrict__ Bt,
    const float* __restrict__ bias, unsigned short* __restrict__ up_t) {
  __shared__ unsigned short Ar[4][8192];   // 4 x (256x32)
  __shared__ unsigned short Br[4][8192];
  const int tid = threadIdx.x, lane = tid & 63, wv = tid >> 6;
  const int wm = wv >> 2, wn = wv & 3;
  const int swz = (blockIdx.x & 7) * 56 + (blockIdx.x >> 3);   // 448 % 8 == 0
  const int by = swz >> 2, bx = swz & 3;
  const int m0 = by * 256, n0 = bx * 256;

  f32x4 acc[8][4];
#pragma unroll
  for (int i = 0; i < 8; ++i)
#pragma unroll
    for (int j = 0; j < 4; ++j) acc[i][j] = (f32x4){0.f, 0.f, 0.f, 0.f};

  const unsigned short* Abase = A + (size_t)m0 * 1024;
  const unsigned short* Bbase = Bt + (size_t)n0 * 1024;
  const int lr = lane & 15, lq = (lane >> 4) * 8;

  // prologue: tiles 0,1,2 (A,B interleaved, oldest first) = 12 loads
  stage256x32_t512(Abase + 0 * 32, 1024, Ar[0], tid);
  stage256x32_t512(Bbase + 0 * 32, 1024, Br[0], tid);
  stage256x32_t512(Abase + 1 * 32, 1024, Ar[1], tid);
  stage256x32_t512(Bbase + 1 * 32, 1024, Br[1], tid);
  stage256x32_t512(Abase + 2 * 32, 1024, Ar[2], tid);
  stage256x32_t512(Bbase + 2 * 32, 1024, Br[2], tid);
  gate<8>();                         // tile 0's 4 loads drained
  __builtin_amdgcn_s_barrier();      // publish tile 0
  __builtin_amdgcn_sched_barrier(0);

  for (int t = 0; t < 32; ++t) {
    const unsigned short* Ab = Ar[t & 3];
    const unsigned short* Bb = Br[t & 3];
    bf16x8 b[4], a0[4], a1[4];
    // ---- ph0 pre-window: reads + stage A(t+3) ----
#pragma unroll
    for (int n = 0; n < 4; ++n) b[n] = lds_fragH(Bb, wn * 64 + n * 16 + lr, lq);
#pragma unroll
    for (int i = 0; i < 4; ++i) a0[i] = lds_fragH(Ab, wm * 128 + i * 16 + lr, lq);
    if (t + 3 < 32) stage256x32_t512(Abase + (t + 3) * 32, 1024, Ar[(t + 3) & 3], tid);
    __builtin_amdgcn_sched_barrier(0);
    __builtin_amdgcn_s_barrier();
    asm volatile("s_waitcnt lgkmcnt(0)" ::: "memory");
    __builtin_amdgcn_sched_barrier(0);
    __builtin_amdgcn_s_setprio(1);
#pragma unroll
    for (int i = 0; i < 4; ++i)
#pragma unroll
      for (int n = 0; n < 4; ++n)
        acc[i][n] = __builtin_amdgcn_mfma_f32_16x16x32_bf16(a0[i], b[n], acc[i][n], 0, 0, 0);
    __builtin_amdgcn_s_setprio(0);
    // ---- ph1 pre-window: reads + stage B(t+3) + gate for t+1 ----
#pragma unroll
    for (int i = 0; i < 4; ++i) a1[i] = lds_fragH(Ab, wm * 128 + (4 + i) * 16 + lr, lq);
    if (t + 3 < 32) stage256x32_t512(Bbase + (t + 3) * 32, 1024, Br[(t + 3) & 3], tid);
    if (t + 1 < 32) {
      if (t <= 28) gate<8>();
      else if (t == 29) gate<4>();
      else gate<0>();
    }
    __builtin_amdgcn_sched_barrier(0);
    __builtin_amdgcn_s_barrier();
    asm volatile("s_waitcnt lgkmcnt(0)" ::: "memory");
    __builtin_amdgcn_sched_barrier(0);
    __builtin_amdgcn_s_setprio(1);
#pragma unroll
    for (int i = 0; i < 4; ++i)
#pragma unroll
      for (int n = 0; n < 4; ++n)
        acc[4 + i][n] = __builtin_amdgcn_mfma_f32_16x16x32_bf16(a1[i], b[n], acc[4 + i][n], 0, 0, 0);
    __builtin_amdgcn_s_setprio(0);
  }

#pragma unroll
  for (int ni = 0; ni < 4; ++ni) {
    int np = n0 + wn * 64 + ni * 16 + (lane & 15);
    int o = (np & 63) * 16 + (np >> 6);
    float bv = bias[o];
#pragma unroll
    for (int mi = 0; mi < 8; ++mi)
#pragma unroll
      for (int r = 0; r < 4; ++r) {
        int m = m0 + wm * 128 + mi * 16 + (lane >> 4) * 4 + r;
        float v = acc[mi][ni][r] + bv;
        v = v / (1.f + fabsf(v));
        up_t[(size_t)m * 1024 + np] = f2b(v);
      }
  }
}

// ---------------------------------------------------------------------------
// dc_fused (verified R10-R14)
// ---------------------------------------------------------------------------
__global__ __launch_bounds__(256) void dc_fused_kernel(
    const unsigned short* __restrict__ up_t,
    const float* __restrict__ w3, const float* __restrict__ b3,
    const float* __restrict__ w1, const float* __restrict__ b1,
    const float* __restrict__ w2, const float* __restrict__ b2,
    float* __restrict__ out) {
  __shared__ unsigned short y1L[576 * 40];
  __shared__ unsigned short y2L[704 * 24];
  const int tid = threadIdx.x, lane = tid & 63, wv = tid >> 6;
  const int g0 = blockIdx.x * 32;
  const int kq = (lane >> 4) * 8;
  const int oc = lane & 15;

  {
    bf16x8 bf[2][6];
#pragma unroll
    for (int nt = 0; nt < 2; ++nt)
#pragma unroll
      for (int kk = 0; kk < 6; ++kk) {
        bf16x8 v;
#pragma unroll
        for (int t = 0; t < 8; ++t) {
          int k = kk * 32 + kq + t;
          int jj = k >> 6, ic = k & 63;
          v[t] = (short)f2b(w3[((size_t)ic * 32 + nt * 16 + oc) * 3 + jj]);
        }
        bf[nt][kk] = v;
      }
    const float bia0 = b3[oc], bia1 = b3[16 + oc];
    for (int c = wv; c < 36; c += 4) {
      int m = c * 16 + (lane & 15);
      int imgl = m / 18, ow = m - imgl * 18;
      const unsigned short* arow = up_t + (size_t)(g0 + imgl) * 1024;
      f32x4 acc0 = {0.f, 0.f, 0.f, 0.f}, acc1 = {0.f, 0.f, 0.f, 0.f};
#pragma unroll
      for (int kk = 0; kk < 6; ++kk) {
        int jj = kk >> 1;
        int ic0 = (kk & 1) * 32 + kq;
        int iw = ow - jj;
        bf16x8 a = {0, 0, 0, 0, 0, 0, 0, 0};
        if ((unsigned)iw < 16u) a = *(const bf16x8*)(arow + iw * 64 + ic0);
        acc0 = __builtin_amdgcn_mfma_f32_16x16x32_bf16(a, bf[0][kk], acc0, 0, 0, 0);
        acc1 = __builtin_amdgcn_mfma_f32_16x16x32_bf16(a, bf[1][kk], acc1, 0, 0, 0);
      }
#pragma unroll
      for (int r = 0; r < 4; ++r) {
        int mm = c * 16 + (lane >> 4) * 4 + r;
        float v0 = acc0[r] + bia0; v0 = v0 > 0.f ? v0 : 0.01f * v0;
        float v1 = acc1[r] + bia1; v1 = v1 > 0.f ? v1 : 0.01f * v1;
        y1L[mm * 40 + oc] = f2b(v0);
        y1L[mm * 40 + 16 + oc] = f2b(v1);
      }
    }
  }
  __syncthreads();

  {
    bf16x8 bf[5];
#pragma unroll
    for (int kk = 0; kk < 5; ++kk) {
      bf16x8 v;
#pragma unroll
      for (int t = 0; t < 8; ++t) {
        int ic = kq + t;
        v[t] = (short)f2b(w1[((size_t)ic * 16 + oc) * 5 + kk]);
      }
      bf[kk] = v;
    }
    const float bia = b1[oc];
    for (int c = wv; c < 44; c += 4) {
      int m = c * 16 + (lane & 15);
      int imgl = m / 22, ow = m - imgl * 22;
      const unsigned short* abase = y1L + imgl * (18 * 40);
      f32x4 acc = {0.f, 0.f, 0.f, 0.f};
#pragma unroll
      for (int kk = 0; kk < 5; ++kk) {
        int iw = ow - kk;
        bf16x8 a = {0, 0, 0, 0, 0, 0, 0, 0};
        if ((unsigned)iw < 18u) a = *(const bf16x8*)(abase + iw * 40 + kq);
        acc = __builtin_amdgcn_mfma_f32_16x16x32_bf16(a, bf[kk], acc, 0, 0, 0);
      }
#pragma unroll
      for (int r = 0; r < 4; ++r) {
        int mm = c * 16 + (lane >> 4) * 4 + r;
        float v = acc[r] + bia;
        v = v > 0.f ? v : 0.01f * v;
        y2L[mm * 24 + oc] = f2b(v);
      }
    }
  }
  __syncthreads();

  for (int ii = tid; ii < 768; ii += 256) {
    int imgl = ii / 24, ow = ii - imgl * 24;
    float lg0 = b2[0], lg1 = b2[0], lg2 = b2[0];
#pragma unroll
    for (int jj = 0; jj < 3; ++jj) {
      int iw = ow - jj;
      if ((unsigned)iw >= 22u) continue;
      const unsigned short* row = y2L + (imgl * 22 + iw) * 24;
      bf16x8 v0 = *(const bf16x8*)(row);
      bf16x8 v1 = *(const bf16x8*)(row + 8);
      float x[16];
#pragma unroll
      for (int ic = 0; ic < 8; ++ic) {
        x[ic] = b2f((unsigned short)v0[ic]);
        x[8 + ic] = b2f((unsigned short)v1[ic]);
      }
#pragma unroll
      for (int ic = 0; ic < 16; ++ic) {
        lg0 += x[ic] * w2[ic * 9 + 0 * 3 + jj];
        lg1 += x[ic] * w2[ic * 9 + 1 * 3 + jj];
        lg2 += x[ic] * w2[ic * 9 + 2 * 3 + jj];
      }
    }
    lg0 = lg0 > 0.f ? lg0 : 0.01f * lg0;
    lg1 = lg1 > 0.f ? lg1 : 0.01f * lg1;
    lg2 = lg2 > 0.f ? lg2 : 0.01f * lg2;
    float mx = fmaxf(lg0, fmaxf(lg1, lg2));
    float e0 = __expf(lg0 - mx), e1 = __expf(lg1 - mx), e2 = __expf(lg2 - mx);
    float inv = 1.f / (e0 + e1 + e2);
    size_t ob = (size_t)(g0 + imgl) * 72 + ow;
    out[ob] = e0 * inv;
    out[ob + 24] = e1 * inv;
    out[ob + 48] = e2 * inv;
  }
}

// ---------------------------------------------------------------------------
extern "C" void kernel_launch(void* const* d_in, const int* in_sizes, int n_in,
                              void* d_out, int out_size, void* d_ws, size_t ws_size,
                              hipStream_t stream) {
  (void)in_sizes; (void)n_in; (void)out_size; (void)ws_size;
  const float* enc    = (const float*)d_in[0];
  const float* noise  = (const float*)d_in[1];
  const float* erep_w = (const float*)d_in[2];
  const float* erep_b = (const float*)d_in[3];
  const float* wih_f  = (const float*)d_in[4];
  const float* whh_f  = (const float*)d_in[5];
  const float* bih_f  = (const float*)d_in[6];
  const float* bhh_f  = (const float*)d_in[7];
  const float* wih_b  = (const float*)d_in[8];
  const float* whh_b  = (const float*)d_in[9];
  const float* bih_b  = (const float*)d_in[10];
  const float* bhh_b  = (const float*)d_in[11];
  const float* emb_w  = (const float*)d_in[12];
  const float* emb_b  = (const float*)d_in[13];
  const float* dc3w   = (const float*)d_in[14];
  const float* dc3b   = (const float*)d_in[15];
  const float* dc1w   = (const float*)d_in[16];
  const float* dc1b   = (const float*)d_in[17];
  const float* dc2w   = (const float*)d_in[18];
  const float* dc2b   = (const float*)d_in[19];
  float* out = (float*)d_out;

  char* p = (char*)d_ws;
  auto carve = [&p](size_t bytes) {
    char* r = p;
    p += (bytes + 255) & ~(size_t)255;
    return r;
  };
  unsigned short* rep_t  = (unsigned short*)carve(7ull * 4096 * 256 * 2);
  unsigned short* lstmW  = (unsigned short*)carve(2ull * 2048 * 768 * 2);
  float*          lstmB  = (float*)carve(2ull * 2048 * 4);
  unsigned short* noiseb = (unsigned short*)carve(4096ull * 256 * 2);
  unsigned short* erepT  = (unsigned short*)carve(1792ull * 256 * 2);
  unsigned short* embT   = (unsigned short*)carve(1024ull * 1024 * 2);
  unsigned short* cbuf   = (unsigned short*)carve(2ull * 4096 * 512 * 2);
  unsigned short* lstm1  = (unsigned short*)carve(4096ull * 7 * 1024 * 2);
  unsigned short* att    = (unsigned short*)carve(28672ull * 1024 * 2);
  unsigned short* up_t   = (unsigned short*)carve(28672ull * 1024 * 2);

  pack_kernel<<<2048, 256, 0, stream>>>(noise, erep_w, emb_w, wih_f, whh_f, bih_f, bhh_f,
                                        wih_b, whh_b, bih_b, bhh_b,
                                        noiseb, erepT, embT, lstmW, lstmB);
  gemm_rep_kernel<<<dim3(14, 32), 256, 0, stream>>>(noiseb, erepT, erep_b, rep_t);
  lstm_step_kernel<8><<<512, 256, 0, stream>>>(rep_t, lstmW, lstmB, cbuf, lstm1, 0);
  for (int s = 1; s < 7; ++s)
    lstm_step_kernel<24><<<512, 256, 0, stream>>>(rep_t, lstmW, lstmB, cbuf, lstm1, s);
  att_fused3_kernel<<<4096, 256, 0, stream>>>(enc, lstm1, att);
  gemm_emb8p_kernel<<<448, 512, 0, stream>>>(att, embT, emb_b, up_t);
  dc_fused_kernel<<<896, 256, 0, stream>>>(up_t, dc3w, dc3b, dc1w, dc1b, dc2w, dc2b, out);
}

// Round 16
// 463.400 us; speedup vs baseline: 1.0133x; 1.0133x over previous
//
#include <hip/hip_runtime.h>
#include <stdint.h>

// ---------------------------------------------------------------------------
// decoder_80487687127254 : B=4096 T=7 H=512 L=256 D=1024
// ---------------------------------------------------------------------------

typedef __attribute__((ext_vector_type(4))) float f32x4;
typedef __attribute__((ext_vector_type(8))) short bf16x8;
typedef __attribute__((ext_vector_type(4))) unsigned short us4;

__device__ __forceinline__ unsigned short f2b(float f) {
  union { float f; unsigned u; } x; x.f = f;
  unsigned r = x.u + 0x7FFFu + ((x.u >> 16) & 1u);   // RNE
  return (unsigned short)(r >> 16);
}
__device__ __forceinline__ float b2f(unsigned short s) {
  union { unsigned u; float f; } x; x.u = ((unsigned)s) << 16; return x.f;
}
__device__ __forceinline__ float sigmoidf(float x) {
  return 1.f / (1.f + __expf(-x));
}
__device__ __forceinline__ float fast_tanh(float x) {
  x = fminf(15.f, fmaxf(-15.f, x));
  float e = __expf(2.f * x);
  return (e - 1.f) / (e + 1.f);
}

// async global->LDS, 16B per lane; LDS dest must be wave-uniform (HW adds lane*16)
__device__ __forceinline__ void gl_lds16(const void* g, void* l) {
  auto gp = reinterpret_cast<const __attribute__((address_space(1))) unsigned int*>(
      reinterpret_cast<uintptr_t>(g));
  auto lp = reinterpret_cast<__attribute__((address_space(3))) unsigned int*>(
      reinterpret_cast<uintptr_t>(l));
  __builtin_amdgcn_global_load_lds(gp, lp, 16, 0, 0);
}

// ===========================================================================
// 2-phase GEMM cores (wave tile 128x64, BK=32, dbuf).  The plateau structure:
// 15 rounds of schedule variants (ring2/3/4, counted vmcnt, pre-barrier
// reads, 8-phase x4) ALL land at 25-29% MfmaUtil ~= 670 TF, matching the
// guide's measured 2-phase reference (m248v2: 666 TF).  Structural floor:
// 227 GF GEMM work / 670 TF ~= 339 us.  R16: setprio removed from the MFMA
// cluster (guide m190: setprio is NEGATIVE on lockstep 2-phase structures).
// ===========================================================================

// stage a 256x32 tile (16 KB): 4 gl_lds per thread (256 threads).
__device__ __forceinline__ void stage256x32(const unsigned short* src, int ld,
                                            unsigned short* hbase, int tid) {
  const int row_in = tid >> 2;   // 0..63
  const int gidx = tid & 3;
#pragma unroll
  for (int r = 0; r < 4; ++r) {
    int row = r * 64 + row_in;
    int gsrc = gidx ^ ((row >> 1) & 3);
    gl_lds16(src + (size_t)row * ld + gsrc * 8, hbase + r * 2048 + (tid >> 6) * 512);
  }
}

// stage a 128x32 tile (8 KB): 2 gl_lds per thread (256 threads).
__device__ __forceinline__ void stage128x32(const unsigned short* src, int ld,
                                            unsigned short* hbase, int tid) {
  const int row_in = tid >> 2;   // 0..63
  const int gidx = tid & 3;
#pragma unroll
  for (int r = 0; r < 2; ++r) {
    int row = r * 64 + row_in;
    int gsrc = gidx ^ ((row >> 1) & 3);
    gl_lds16(src + (size_t)row * ld + gsrc * 8, hbase + r * 2048 + (tid >> 6) * 512);
  }
}

__device__ __forceinline__ bf16x8 lds_fragH(const unsigned short* hbase, int row, int lq) {
  return *(const bf16x8*)(hbase + row * 32 + (lq ^ (((row >> 1) & 3) << 3)));
}

// one K-tile (BK=32), wave tile 128x64: 12 ds_read_b128 + 32 MFMA.
__device__ __forceinline__ void tile_w128(const unsigned short* Ab, const unsigned short* Bb,
                                          int wm, int wn, int lane, f32x4 (&acc)[8][4]) {
  const int lr = lane & 15, lq = (lane >> 4) * 8;
  bf16x8 b[4];
#pragma unroll
  for (int n = 0; n < 4; ++n) b[n] = lds_fragH(Bb, wn * 64 + n * 16 + lr, lq);
  bf16x8 a[8];
#pragma unroll
  for (int i = 0; i < 8; ++i) a[i] = lds_fragH(Ab, wm * 128 + i * 16 + lr, lq);
#pragma unroll
  for (int i = 0; i < 8; ++i)
#pragma unroll
    for (int n = 0; n < 4; ++n)
      acc[i][n] = __builtin_amdgcn_mfma_f32_16x16x32_bf16(a[i], b[n], acc[i][n], 0, 0, 0);
}

#define DBUF_SYNC()                                   \
  asm volatile("s_waitcnt vmcnt(0)" ::: "memory");    \
  __builtin_amdgcn_s_barrier();                       \
  __builtin_amdgcn_sched_barrier(0);

// ---------------------------------------------------------------------------
// legacy 128x128 2-phase BK=64 core (kept for gemm_rep)
// ---------------------------------------------------------------------------
__device__ __forceinline__ void stage128x64(const unsigned short* src, int ld,
                                            unsigned short* lds, int wv, int lane) {
#pragma unroll
  for (int r = 0; r < 4; ++r) {
    int row = r * 32 + wv * 8 + (lane >> 3);
    gl_lds16(src + (size_t)row * ld + (lane & 7) * 8, lds + (r * 32 + wv * 8) * 64);
  }
}
__device__ __forceinline__ void mfma_tile(const unsigned short* As, const unsigned short* Bs,
                                          int wm, int wn, int lane, f32x4 acc[4][4]) {
#pragma unroll
  for (int kk = 0; kk < 2; ++kk) {
    int ko = kk * 32 + (lane >> 4) * 8;
    bf16x8 a[4], b[4];
#pragma unroll
    for (int i = 0; i < 4; ++i)
      a[i] = *(const bf16x8*)(As + (size_t)(wm * 64 + i * 16 + (lane & 15)) * 64 + ko);
#pragma unroll
    for (int i = 0; i < 4; ++i)
      b[i] = *(const bf16x8*)(Bs + (size_t)(wn * 64 + i * 16 + (lane & 15)) * 64 + ko);
#pragma unroll
    for (int mi = 0; mi < 4; ++mi)
#pragma unroll
      for (int ni = 0; ni < 4; ++ni)
        acc[mi][ni] = __builtin_amdgcn_mfma_f32_16x16x32_bf16(a[mi], b[ni], acc[mi][ni], 0, 0, 0);
  }
}

// ---------------------------------------------------------------------------
// pack, x4-vectorized (verified R13/R14)
// ---------------------------------------------------------------------------
__global__ __launch_bounds__(256) void pack_kernel(
    const float* __restrict__ noise, const float* __restrict__ erep_w,
    const float* __restrict__ emb_w,
    const float* __restrict__ wih_f, const float* __restrict__ whh_f,
    const float* __restrict__ bih_f, const float* __restrict__ bhh_f,
    const float* __restrict__ wih_b, const float* __restrict__ whh_b,
    const float* __restrict__ bih_b, const float* __restrict__ bhh_b,
    unsigned short* __restrict__ noiseb, unsigned short* __restrict__ erepT,
    unsigned short* __restrict__ embT, unsigned short* __restrict__ lstmW,
    float* __restrict__ lstmB) {
  const int N0 = 4096 * 256 / 4;
  const int N1 = 1792 * 256 / 4;
  const int N2 = 1024 * 1024 / 4;
  const int N3 = 2 * 2048 * 768 / 4;
  const int N4 = 2 * 2048 / 4;
  const int total = N0 + N1 + N2 + N3 + N4;
  for (int i = blockIdx.x * 256 + threadIdx.x; i < total; i += gridDim.x * 256) {
    int x = i;
    if (x < N0) {
      f32x4 v = ((const f32x4*)noise)[x];
      us4 o4;
#pragma unroll
      for (int e = 0; e < 4; ++e) o4[e] = f2b(v[e]);
      ((us4*)noiseb)[x] = o4;
      continue;
    }
    x -= N0;
    if (x < N1) {
      int n = x >> 6, k4 = (x & 63) * 4;
      us4 o4;
#pragma unroll
      for (int e = 0; e < 4; ++e) o4[e] = f2b(erep_w[(size_t)(k4 + e) * 1792 + n]);
      ((us4*)erepT)[x] = o4;
      continue;
    }
    x -= N1;
    if (x < N2) {
      int n = x >> 8, k4 = (x & 255) * 4;
      int o = (n & 63) * 16 + (n >> 6);
      us4 o4;
#pragma unroll
      for (int e = 0; e < 4; ++e) o4[e] = f2b(emb_w[(size_t)(k4 + e) * 1024 + o]);
      ((us4*)embT)[x] = o4;
      continue;
    }
    x -= N2;
    if (x < N3) {
      int dir = x / (2048 * 192);
      int r = x - dir * (2048 * 192);
      int npk = r / 192, k4 = (r - npk * 192) * 4;
      int blk = npk >> 6, g = (npk >> 4) & 3, u = npk & 15;
      int o = g * 512 + blk * 16 + u;
      const float* wih = dir ? wih_b : wih_f;
      const float* whh = dir ? whh_b : whh_f;
      us4 o4;
#pragma unroll
      for (int e = 0; e < 4; ++e) {
        int k = k4 + e;
        float v = (k < 256) ? wih[(size_t)k * 2048 + o] : whh[(size_t)(k - 256) * 2048 + o];
        o4[e] = f2b(v);
      }
      ((us4*)lstmW)[x] = o4;
      continue;
    }
    x -= N3;
    {
      int dir = x >> 9, npk4 = (x & 511) * 4;
      int blk = npk4 >> 6, g = (npk4 >> 4) & 3, u = npk4 & 15;
      int o = g * 512 + blk * 16 + u;
      const float* bi = dir ? bih_b : bih_f;
      const float* bh = dir ? bhh_b : bhh_f;
      f32x4 o4;
#pragma unroll
      for (int e = 0; e < 4; ++e) o4[e] = bi[o + e] + bh[o + e];
      ((f32x4*)lstmB)[x] = o4;
    }
  }
}

// ---------------------------------------------------------------------------
// rep = softsign(noise @ erep_w + b)
// ---------------------------------------------------------------------------
__global__ __launch_bounds__(256) void gemm_rep_kernel(
    const unsigned short* __restrict__ A, const unsigned short* __restrict__ Bt,
    const float* __restrict__ bias, unsigned short* __restrict__ rep_t) {
  __shared__ unsigned short As[128 * 64];
  __shared__ unsigned short Bs[128 * 64];
  const int lane = threadIdx.x & 63, wv = threadIdx.x >> 6;
  const int wm = wv >> 1, wn = wv & 1;
  const int m0 = blockIdx.y * 128, n0 = blockIdx.x * 128;
  f32x4 acc[4][4];
#pragma unroll
  for (int i = 0; i < 4; ++i)
#pragma unroll
    for (int j = 0; j < 4; ++j) acc[i][j] = (f32x4){0.f, 0.f, 0.f, 0.f};
  for (int k0 = 0; k0 < 256; k0 += 64) {
    stage128x64(A + (size_t)m0 * 256 + k0, 256, As, wv, lane);
    stage128x64(Bt + (size_t)n0 * 256 + k0, 256, Bs, wv, lane);
    __syncthreads();
    mfma_tile(As, Bs, wm, wn, lane, acc);
    __syncthreads();
  }
#pragma unroll
  for (int ni = 0; ni < 4; ++ni) {
    int n = n0 + wn * 64 + ni * 16 + (lane & 15);
    float bv = bias[n];
    int t = n >> 8, l = n & 255;
#pragma unroll
    for (int mi = 0; mi < 4; ++mi)
#pragma unroll
      for (int r = 0; r < 4; ++r) {
        int m = m0 + wm * 64 + mi * 16 + (lane >> 4) * 4 + r;
        float v = acc[mi][ni][r] + bv;
        v = v / (1.f + fabsf(v));
        rep_t[((size_t)t * 4096 + m) * 256 + l] = f2b(v);
      }
  }
}

// ---------------------------------------------------------------------------
// LSTM step (R14 shape): 256x128 block / 128x64 wave 2-phase core.
// NT=8 (step 0: h0=c0=0) or NT=24.  h read directly from lstm1.
// ---------------------------------------------------------------------------
template <int NT>
__global__ __launch_bounds__(256, 2) void lstm_step_kernel(
    const unsigned short* __restrict__ rep_t, const unsigned short* __restrict__ Wp,
    const float* __restrict__ biasP, unsigned short* __restrict__ cbuf,
    unsigned short* __restrict__ lstm1, int step) {
  __shared__ unsigned short Ar[2][8192];
  __shared__ unsigned short Br[2][4096];
  const int tid = threadIdx.x, lane = tid & 63, wv = tid >> 6;
  const int wm = wv >> 1, wn = wv & 1;
  const int swz = (blockIdx.x & 7) * 64 + (blockIdx.x >> 3);
  const int dir = swz >> 8;
  const int rem = swz & 255;
  const int by = rem >> 4, bx = rem & 15;
  const int m0 = by * 256, n0 = bx * 128;
  const int t_proc = dir ? (6 - step) : step;
  const int t_prev = dir ? (t_proc + 1) : (t_proc - 1);
  const unsigned short* W = Wp + (size_t)dir * 2048 * 768;
  unsigned short* cp = cbuf + (size_t)dir * (4096 * 512);
  const unsigned short* xsrc = rep_t + (size_t)t_proc * 4096 * 256;
  const unsigned short* hsrc =
      lstm1 + (size_t)((NT == 24) ? t_prev : 0) * 1024 + (size_t)dir * 512;

  f32x4 acc[8][4];
#pragma unroll
  for (int i = 0; i < 8; ++i)
#pragma unroll
    for (int j = 0; j < 4; ++j) acc[i][j] = (f32x4){0.f, 0.f, 0.f, 0.f};

  auto asrc = [&](int tt) {
    return tt < 8 ? xsrc + (size_t)m0 * 256 + tt * 32
                  : hsrc + (size_t)m0 * 7168 + (tt - 8) * 32;
  };
  auto ald = [&](int tt) { return tt < 8 ? 256 : 7168; };

  stage256x32(asrc(0), ald(0), Ar[0], tid);
  stage128x32(W + (size_t)n0 * 768 + 0 * 32, 768, Br[0], tid);
  DBUF_SYNC()

#pragma unroll
  for (int t = 0; t < NT; ++t) {
    if (t + 1 < NT) {
      stage256x32(asrc(t + 1), ald(t + 1), Ar[(t + 1) & 1], tid);
      stage128x32(W + (size_t)n0 * 768 + (t + 1) * 32, 768, Br[(t + 1) & 1], tid);
    }
    tile_w128(Ar[t & 1], Br[t & 1], wm, wn, lane, acc);
    if (t + 1 < NT) { DBUF_SYNC() }
  }

  const int u = lane & 15;
  const int blk = (n0 + wn * 64) >> 6;
  const int j = blk * 16 + u;
  const float bz0 = biasP[dir * 2048 + blk * 64 + 0 * 16 + u];
  const float bz1 = biasP[dir * 2048 + blk * 64 + 1 * 16 + u];
  const float bz2 = biasP[dir * 2048 + blk * 64 + 2 * 16 + u];
  const float bz3 = biasP[dir * 2048 + blk * 64 + 3 * 16 + u];
#pragma unroll
  for (int mi = 0; mi < 8; ++mi)
#pragma unroll
    for (int r = 0; r < 4; ++r) {
      int row = m0 + wm * 128 + mi * 16 + (lane >> 4) * 4 + r;
      float gi = acc[mi][0][r] + bz0;
      float gf = acc[mi][1][r] + bz1;
      float gg = acc[mi][2][r] + bz2;
      float go = acc[mi][3][r] + bz3;
      size_t ci = (size_t)row * 512 + j;
      float c;
      if (NT == 8) {
        c = sigmoidf(gi) * fast_tanh(gg);
      } else {
        c = sigmoidf(gf) * b2f(cp[ci]) + sigmoidf(gi) * fast_tanh(gg);
      }
      cp[ci] = f2b(c);
      float h = sigmoidf(go) * fast_tanh(c);
      lstm1[((size_t)row * 7 + t_proc) * 1024 + dir * 512 + j] = f2b(h);
    }
}

// ---------------------------------------------------------------------------
// Fused attention v4: 2 batch rows per block (512 thr), halves independent.
// Per-half structure identical to verified v3 (bf16 E, wave-local staging,
// MFMA Gram, in-LDS recursion).  LDS ~76 KB -> 2 blocks/CU = 16 waves/CU,
// and the two serial recursions (waves 0 and 4) run concurrently.
// ---------------------------------------------------------------------------
__global__ __launch_bounds__(512) void att_fused4_kernel(
    const float* __restrict__ enc, const unsigned short* __restrict__ lstm1,
    unsigned short* __restrict__ att) {
  __shared__ unsigned short Qs[2][7 * 1032];
  __shared__ unsigned short Es[2][7 * 1032];
  __shared__ float P[2][2048];
  __shared__ float sG[2][98];
  __shared__ float sC[2][7][14];
  __shared__ float sA[2][16];
  const int tid = threadIdx.x;
  const int half = tid >> 8, htid = tid & 255;
  const int lane = htid & 63, wv = htid >> 6;
  const int b = blockIdx.x * 2 + half;
  const float* Eb = enc + (size_t)b * 7168;
  const unsigned short* Qb = lstm1 + (size_t)b * 7168;

  if (htid < 98) ((float*)sC[half])[htid] = 0.f;

  // ---- stage: thread htid owns dims [4*htid, 4*htid+4) for all 7 rows ----
  const f32x4* Eb4 = (const f32x4*)Eb;
  const int d0 = htid * 4;
#pragma unroll
  for (int r = 0; r < 7; ++r) {
    f32x4 v = Eb4[r * 256 + htid];
    us4 hi;
#pragma unroll
    for (int e = 0; e < 4; ++e) hi[e] = f2b(v[e]);
    *(us4*)&Es[half][r * 1032 + d0] = hi;
    *(us4*)&Qs[half][r * 1032 + d0] = *(const us4*)(Qb + r * 1024 + d0);
  }
  // wave-local: Gram reads only this wave's 256-dim slice -> lgkm drain only
  asm volatile("s_waitcnt lgkmcnt(0)" ::: "memory");
  __builtin_amdgcn_sched_barrier(0);

  // ---- Gram via MFMA: wave wv covers k in [wv*256, wv*256+256) ----
  {
    const int rr = lane & 15;
    const int rowc = rr % 7;
    const int kbase = wv * 256 + (lane >> 4) * 8;
    f32x4 g1 = {0.f, 0.f, 0.f, 0.f}, g2 = {0.f, 0.f, 0.f, 0.f};
#pragma unroll
    for (int s = 0; s < 8; ++s) {
      const int k0 = kbase + s * 32;
      bf16x8 aq = *(const bf16x8*)&Qs[half][rowc * 1032 + k0];
      bf16x8 be = *(const bf16x8*)&Es[half][rowc * 1032 + k0];
      g1 = __builtin_amdgcn_mfma_f32_16x16x32_bf16(aq, be, g1, 0, 0, 0);
      g2 = __builtin_amdgcn_mfma_f32_16x16x32_bf16(aq, aq, g2, 0, 0, 0);
    }
    *(f32x4*)&P[half][((wv * 2 + 0) * 64 + lane) * 4] = g1;
    *(f32x4*)&P[half][((wv * 2 + 1) * 64 + lane) * 4] = g2;
  }
  __syncthreads();

  // ---- gather G + recursion (per-half wave 0) ----
  if (htid < 98) {
    int i = htid / 14, v = htid - i * 14;
    int col = v < 7 ? v : v - 7;
    int tile = v < 7 ? 0 : 1;
    int ln = ((i >> 2) << 4) | col;
    int rg = i & 3;
    float s = 0.f;
#pragma unroll
    for (int w = 0; w < 4; ++w) s += P[half][((w * 2 + tile) * 64 + ln) * 4 + rg];
    sG[half][i * 14 + v] = s;
  }
  __syncthreads();
  if (wv == 0) {
    for (int i = 0; i < 7; ++i) {
      const int nt = 7 + i;
      float s = -1e30f;
      if (lane < 7) {
        s = sG[half][i * 14 + lane];
      } else if (lane < nt) {
        int jj = lane - 7;
        float a2 = 0.f;
#pragma unroll
        for (int v = 0; v < 14; ++v) a2 += sC[half][jj][v] * sG[half][i * 14 + v];
        s = a2;
      }
      float mx = s;
#pragma unroll
      for (int off = 8; off >= 1; off >>= 1) mx = fmaxf(mx, __shfl_xor(mx, off, 16));
      float e = (lane < nt) ? __expf(s - mx) : 0.f;
      float sum = e;
#pragma unroll
      for (int off = 8; off >= 1; off >>= 1) sum += __shfl_xor(sum, off, 16);
      float aw = e / sum;
      if (lane < 16) sA[half][lane] = aw;
      if (lane < 14) {
        float c = (lane < 7) ? sA[half][lane] : 0.f;
        for (int jj = 0; jj < i; ++jj) c += sA[half][7 + jj] * sC[half][jj][lane];
        if (lane == 7 + i) c += 1.f;
        sC[half][i][lane] = c;
      }
    }
  }
  __syncthreads();

  // ---- output: att[i][d] = sum_v C[i][v]*basis[v][d] (thread-local reads) ----
  {
    float acc[7][4];
#pragma unroll
    for (int i = 0; i < 7; ++i)
#pragma unroll
      for (int e = 0; e < 4; ++e) acc[i][e] = 0.f;
#pragma unroll
    for (int t = 0; t < 7; ++t) {
      us4 ev = *(const us4*)&Es[half][t * 1032 + d0];
      float evf[4];
#pragma unroll
      for (int e = 0; e < 4; ++e) evf[e] = b2f(ev[e]);
#pragma unroll
      for (int i = 0; i < 7; ++i) {
        float c = sC[half][i][t];
#pragma unroll
        for (int e = 0; e < 4; ++e) acc[i][e] += c * evf[e];
      }
    }
#pragma unroll
    for (int m = 0; m < 7; ++m) {
      us4 qv = *(const us4*)&Qs[half][m * 1032 + d0];
      float qf[4];
#pragma unroll
      for (int e = 0; e < 4; ++e) qf[e] = b2f(qv[e]);
#pragma unroll
      for (int i = m; i < 7; ++i) {   // sC[i][7+m]==0 for i<m
        float c = sC[half][i][7 + m];
#pragma unroll
        for (int e = 0; e < 4; ++e) acc[i][e] += c * qf[e];
      }
    }
    unsigned short* Ab = att + (size_t)b * 7168;
#pragma unroll
    for (int i = 0; i < 7; ++i) {
      us4 r;
#pragma unroll
      for (int e = 0; e < 4; ++e) r[e] = f2b(acc[i][e]);
      *(us4*)(Ab + i * 1024 + d0) = r;
    }
  }
}

// ---------------------------------------------------------------------------
// up_t = softsign(att @ emb_w + emb_b), 256x128 block / 128x64 wave 2-phase.
// K=1024 -> 32 tiles.  Grid 896 (112 M x 8 N), XCD-swizzled.  (R14 core)
// ---------------------------------------------------------------------------
__global__ __launch_bounds__(256, 2) void gemm_emb_kernel(
    const unsigned short* __restrict__ A, const unsigned short* __restrict__ Bt,
    const float* __restrict__ bias, unsigned short* __restrict__ up_t) {
  __shared__ unsigned short Ar[2][8192];
  __shared__ unsigned short Br[2][4096];
  const int tid = threadIdx.x, lane = tid & 63, wv = tid >> 6;
  const int wm = wv >> 1, wn = wv & 1;
  const int swz = (blockIdx.x & 7) * 112 + (blockIdx.x >> 3);   // 896 % 8 == 0
  const int by = swz >> 3, bx = swz & 7;
  const int m0 = by * 256, n0 = bx * 128;

  f32x4 acc[8][4];
#pragma unroll
  for (int i = 0; i < 8; ++i)
#pragma unroll
    for (int j = 0; j < 4; ++j) acc[i][j] = (f32x4){0.f, 0.f, 0.f, 0.f};

  const unsigned short* Abase = A + (size_t)m0 * 1024;
  const unsigned short* Bbase = Bt + (size_t)n0 * 1024;

  stage256x32(Abase + 0 * 32, 1024, Ar[0], tid);
  stage128x32(Bbase + 0 * 32, 1024, Br[0], tid);
  DBUF_SYNC()

#pragma unroll
  for (int t = 0; t < 32; ++t) {
    if (t + 1 < 32) {
      stage256x32(Abase + (t + 1) * 32, 1024, Ar[(t + 1) & 1], tid);
      stage128x32(Bbase + (t + 1) * 32, 1024, Br[(t + 1) & 1], tid);
    }
    tile_w128(Ar[t & 1], Br[t & 1], wm, wn, lane, acc);
    if (t + 1 < 32) { DBUF_SYNC() }
  }

#pragma unroll
  for (int ni = 0; ni < 4; ++ni) {
    int np = n0 + wn * 64 + ni * 16 + (lane & 15);
    int o = (np & 63) * 16 + (np >> 6);
    float bv = bias[o];
#pragma unroll
    for (int mi = 0; mi < 8; ++mi)
#pragma unroll
      for (int r = 0; r < 4; ++r) {
        int m = m0 + wm * 128 + mi * 16 + (lane >> 4) * 4 + r;
        float v = acc[mi][ni][r] + bv;
        v = v / (1.f + fabsf(v));
        up_t[(size_t)m * 1024 + np] = f2b(v);
      }
  }
}

// ---------------------------------------------------------------------------
// dc_fused (verified R10-R15)
// ---------------------------------------------------------------------------
__global__ __launch_bounds__(256) void dc_fused_kernel(
    const unsigned short* __restrict__ up_t,
    const float* __restrict__ w3, const float* __restrict__ b3,
    const float* __restrict__ w1, const float* __restrict__ b1,
    const float* __restrict__ w2, const float* __restrict__ b2,
    float* __restrict__ out) {
  __shared__ unsigned short y1L[576 * 40];
  __shared__ unsigned short y2L[704 * 24];
  const int tid = threadIdx.x, lane = tid & 63, wv = tid >> 6;
  const int g0 = blockIdx.x * 32;
  const int kq = (lane >> 4) * 8;
  const int oc = lane & 15;

  {
    bf16x8 bf[2][6];
#pragma unroll
    for (int nt = 0; nt < 2; ++nt)
#pragma unroll
      for (int kk = 0; kk < 6; ++kk) {
        bf16x8 v;
#pragma unroll
        for (int t = 0; t < 8; ++t) {
          int k = kk * 32 + kq + t;
          int jj = k >> 6, ic = k & 63;
          v[t] = (short)f2b(w3[((size_t)ic * 32 + nt * 16 + oc) * 3 + jj]);
        }
        bf[nt][kk] = v;
      }
    const float bia0 = b3[oc], bia1 = b3[16 + oc];
    for (int c = wv; c < 36; c += 4) {
      int m = c * 16 + (lane & 15);
      int imgl = m / 18, ow = m - imgl * 18;
      const unsigned short* arow = up_t + (size_t)(g0 + imgl) * 1024;
      f32x4 acc0 = {0.f, 0.f, 0.f, 0.f}, acc1 = {0.f, 0.f, 0.f, 0.f};
#pragma unroll
      for (int kk = 0; kk < 6; ++kk) {
        int jj = kk >> 1;
        int ic0 = (kk & 1) * 32 + kq;
        int iw = ow - jj;
        bf16x8 a = {0, 0, 0, 0, 0, 0, 0, 0};
        if ((unsigned)iw < 16u) a = *(const bf16x8*)(arow + iw * 64 + ic0);
        acc0 = __builtin_amdgcn_mfma_f32_16x16x32_bf16(a, bf[0][kk], acc0, 0, 0, 0);
        acc1 = __builtin_amdgcn_mfma_f32_16x16x32_bf16(a, bf[1][kk], acc1, 0, 0, 0);
      }
#pragma unroll
      for (int r = 0; r < 4; ++r) {
        int mm = c * 16 + (lane >> 4) * 4 + r;
        float v0 = acc0[r] + bia0; v0 = v0 > 0.f ? v0 : 0.01f * v0;
        float v1 = acc1[r] + bia1; v1 = v1 > 0.f ? v1 : 0.01f * v1;
        y1L[mm * 40 + oc] = f2b(v0);
        y1L[mm * 40 + 16 + oc] = f2b(v1);
      }
    }
  }
  __syncthreads();

  {
    bf16x8 bf[5];
#pragma unroll
    for (int kk = 0; kk < 5; ++kk) {
      bf16x8 v;
#pragma unroll
      for (int t = 0; t < 8; ++t) {
        int ic = kq + t;
        v[t] = (short)f2b(w1[((size_t)ic * 16 + oc) * 5 + kk]);
      }
      bf[kk] = v;
    }
    const float bia = b1[oc];
    for (int c = wv; c < 44; c += 4) {
      int m = c * 16 + (lane & 15);
      int imgl = m / 22, ow = m - imgl * 22;
      const unsigned short* abase = y1L + imgl * (18 * 40);
      f32x4 acc = {0.f, 0.f, 0.f, 0.f};
#pragma unroll
      for (int kk = 0; kk < 5; ++kk) {
        int iw = ow - kk;
        bf16x8 a = {0, 0, 0, 0, 0, 0, 0, 0};
        if ((unsigned)iw < 18u) a = *(const bf16x8*)(abase + iw * 40 + kq);
        acc = __builtin_amdgcn_mfma_f32_16x16x32_bf16(a, bf[kk], acc, 0, 0, 0);
      }
#pragma unroll
      for (int r = 0; r < 4; ++r) {
        int mm = c * 16 + (lane >> 4) * 4 + r;
        float v = acc[r] + bia;
        v = v > 0.f ? v : 0.01f * v;
        y2L[mm * 24 + oc] = f2b(v);
      }
    }
  }
  __syncthreads();

  for (int ii = tid; ii < 768; ii += 256) {
    int imgl = ii / 24, ow = ii - imgl * 24;
    float lg0 = b2[0], lg1 = b2[0], lg2 = b2[0];
#pragma unroll
    for (int jj = 0; jj < 3; ++jj) {
      int iw = ow - jj;
      if ((unsigned)iw >= 22u) continue;
      const unsigned short* row = y2L + (imgl * 22 + iw) * 24;
      bf16x8 v0 = *(const bf16x8*)(row);
      bf16x8 v1 = *(const bf16x8*)(row + 8);
      float x[16];
#pragma unroll
      for (int ic = 0; ic < 8; ++ic) {
        x[ic] = b2f((unsigned short)v0[ic]);
        x[8 + ic] = b2f((unsigned short)v1[ic]);
      }
#pragma unroll
      for (int ic = 0; ic < 16; ++ic) {
        lg0 += x[ic] * w2[ic * 9 + 0 * 3 + jj];
        lg1 += x[ic] * w2[ic * 9 + 1 * 3 + jj];
        lg2 += x[ic] * w2[ic * 9 + 2 * 3 + jj];
      }
    }
    lg0 = lg0 > 0.f ? lg0 : 0.01f * lg0;
    lg1 = lg1 > 0.f ? lg1 : 0.01f * lg1;
    lg2 = lg2 > 0.f ? lg2 : 0.01f * lg2;
    float mx = fmaxf(lg0, fmaxf(lg1, lg2));
    float e0 = __expf(lg0 - mx), e1 = __expf(lg1 - mx), e2 = __expf(lg2 - mx);
    float inv = 1.f / (e0 + e1 + e2);
    size_t ob = (size_t)(g0 + imgl) * 72 + ow;
    out[ob] = e0 * inv;
    out[ob + 24] = e1 * inv;
    out[ob + 48] = e2 * inv;
  }
}

// ---------------------------------------------------------------------------
extern "C" void kernel_launch(void* const* d_in, const int* in_sizes, int n_in,
                              void* d_out, int out_size, void* d_ws, size_t ws_size,
                              hipStream_t stream) {
  (void)in_sizes; (void)n_in; (void)out_size; (void)ws_size;
  const float* enc    = (const float*)d_in[0];
  const float* noise  = (const float*)d_in[1];
  const float* erep_w = (const float*)d_in[2];
  const float* erep_b = (const float*)d_in[3];
  const float* wih_f  = (const float*)d_in[4];
  const float* whh_f  = (const float*)d_in[5];
  const float* bih_f  = (const float*)d_in[6];
  const float* bhh_f  = (const float*)d_in[7];
  const float* wih_b  = (const float*)d_in[8];
  const float* whh_b  = (const float*)d_in[9];
  const float* bih_b  = (const float*)d_in[10];
  const float* bhh_b  = (const float*)d_in[11];
  const float* emb_w  = (const float*)d_in[12];
  const float* emb_b  = (const float*)d_in[13];
  const float* dc3w   = (const float*)d_in[14];
  const float* dc3b   = (const float*)d_in[15];
  const float* dc1w   = (const float*)d_in[16];
  const float* dc1b   = (const float*)d_in[17];
  const float* dc2w   = (const float*)d_in[18];
  const float* dc2b   = (const float*)d_in[19];
  float* out = (float*)d_out;

  char* p = (char*)d_ws;
  auto carve = [&p](size_t bytes) {
    char* r = p;
    p += (bytes + 255) & ~(size_t)255;
    return r;
  };
  unsigned short* rep_t  = (unsigned short*)carve(7ull * 4096 * 256 * 2);
  unsigned short* lstmW  = (unsigned short*)carve(2ull * 2048 * 768 * 2);
  float*          lstmB  = (float*)carve(2ull * 2048 * 4);
  unsigned short* noiseb = (unsigned short*)carve(4096ull * 256 * 2);
  unsigned short* erepT  = (unsigned short*)carve(1792ull * 256 * 2);
  unsigned short* embT   = (unsigned short*)carve(1024ull * 1024 * 2);
  unsigned short* cbuf   = (unsigned short*)carve(2ull * 4096 * 512 * 2);
  unsigned short* lstm1  = (unsigned short*)carve(4096ull * 7 * 1024 * 2);
  unsigned short* att    = (unsigned short*)carve(28672ull * 1024 * 2);
  unsigned short* up_t   = (unsigned short*)carve(28672ull * 1024 * 2);

  pack_kernel<<<2048, 256, 0, stream>>>(noise, erep_w, emb_w, wih_f, whh_f, bih_f, bhh_f,
                                        wih_b, whh_b, bih_b, bhh_b,
                                        noiseb, erepT, embT, lstmW, lstmB);
  gemm_rep_kernel<<<dim3(14, 32), 256, 0, stream>>>(noiseb, erepT, erep_b, rep_t);
  lstm_step_kernel<8><<<512, 256, 0, stream>>>(rep_t, lstmW, lstmB, cbuf, lstm1, 0);
  for (int s = 1; s < 7; ++s)
    lstm_step_kernel<24><<<512, 256, 0, stream>>>(rep_t, lstmW, lstmB, cbuf, lstm1, s);
  att_fused4_kernel<<<2048, 512, 0, stream>>>(enc, lstm1, att);
  gemm_emb_kernel<<<896, 256, 0, stream>>>(att, embT, emb_b, up_t);
  dc_fused_kernel<<<896, 256, 0, stream>>>(up_t, dc3w, dc3b, dc1w, dc1b, dc2w, dc2b, out);
}